// Round 3
// baseline (591.358 us; speedup 1.0000x reference)
//
#include <hip/hip_runtime.h>

// ---------------- types / helpers ----------------
typedef __bf16 bf16x8 __attribute__((ext_vector_type(8)));
typedef float f32x4 __attribute__((ext_vector_type(4)));
typedef unsigned short u16x8 __attribute__((ext_vector_type(8)));

__device__ __forceinline__ unsigned short f2bf(float f) {
  union { float f; unsigned int u; } v; v.f = f;
  unsigned int r = v.u + 0x7fffu + ((v.u >> 16) & 1u);  // RNE
  return (unsigned short)(r >> 16);
}

__device__ __forceinline__ void async16(const unsigned short* g, unsigned short* l) {
  __builtin_amdgcn_global_load_lds(
      (const __attribute__((address_space(1))) unsigned int*)g,
      (__attribute__((address_space(3))) unsigned int*)l, 16, 0, 0);
}

// ---------------- f32 -> bf16 convert (optional scale) ----------------
__global__ void cvt_bf16(const float* __restrict__ s, unsigned short* __restrict__ d, int n4,
                         float scale) {
  int i = blockIdx.x * 256 + threadIdx.x;
  if (i >= n4) return;
  float4 v = ((const float4*)s)[i];
  ushort4 o;
  o.x = f2bf(v.x * scale); o.y = f2bf(v.y * scale);
  o.z = f2bf(v.z * scale); o.w = f2bf(v.w * scale);
  ((ushort4*)d)[i] = o;
}

// ---------------- QKV bias concat (q pre-scaled) ----------------
__global__ void concat_bias(const float* __restrict__ qb, const float* __restrict__ kb,
                            const float* __restrict__ vb, float* __restrict__ o) {
  int i = blockIdx.x * 256 + threadIdx.x;  // 3072
  float v = (i < 1024) ? qb[i] * 0.125f : (i < 2048 ? kb[i - 1024] : vb[i - 2048]);
  o[i] = v;
}

// ---------------- LayerNorm (per 1024-row) -> bf16 ----------------
// PREFILL: also write dout[row] = src[row] + fbias (fc2 bias), for split-K atomic fc2.
template <int PREFILL>
__global__ __launch_bounds__(256) void ln_bf16(
    const float* __restrict__ src, unsigned short* __restrict__ dst,
    const float* __restrict__ g, const float* __restrict__ be,
    const float* __restrict__ fbias, float* __restrict__ dout) {
  const int row = blockIdx.x, tid = threadIdx.x;
  const float4 v = ((const float4*)(src + (size_t)row * 1024))[tid];
  if (PREFILL) {
    const float4 fb = ((const float4*)fbias)[tid];
    float4 r;
    r.x = v.x + fb.x; r.y = v.y + fb.y; r.z = v.z + fb.z; r.w = v.w + fb.w;
    ((float4*)(dout + (size_t)row * 1024))[tid] = r;
  }
  float s = v.x + v.y + v.z + v.w;
  float qq = v.x * v.x + v.y * v.y + v.z * v.z + v.w * v.w;
#pragma unroll
  for (int off = 32; off; off >>= 1) { s += __shfl_xor(s, off); qq += __shfl_xor(qq, off); }
  __shared__ float ps[4], pq[4];
  const int w = tid >> 6, lane = tid & 63;
  if (lane == 0) { ps[w] = s; pq[w] = qq; }
  __syncthreads();
  if (tid == 0) { ps[0] = ps[0] + ps[1] + ps[2] + ps[3]; pq[0] = pq[0] + pq[1] + pq[2] + pq[3]; }
  __syncthreads();
  const float mu = ps[0] * (1.f / 1024.f);
  const float var = pq[0] * (1.f / 1024.f) - mu * mu;
  const float rs = rsqrtf(var + 1e-5f);
  const float4 gv = ((const float4*)g)[tid];
  const float4 bv = ((const float4*)be)[tid];
  ushort4 o;
  o.x = f2bf((v.x - mu) * rs * gv.x + bv.x);
  o.y = f2bf((v.y - mu) * rs * gv.y + bv.y);
  o.z = f2bf((v.z - mu) * rs * gv.z + bv.z);
  o.w = f2bf((v.w - mu) * rs * gv.w + bv.w);
  ((ushort4*)(dst + (size_t)row * 1024))[tid] = o;
}

// ---------------- GEMM: C[M,N] = A[M,K] @ B[N,K]^T (+ bias), m97-style ----------------
// EPI: 2 = acc+bias+resid -> f32 ; 3 = relu(acc+bias) -> bf16 ;
//      5 = fused QKV epilogue -> head-major bf16 (Cout = QB base; K/V at fixed offsets) ;
//      6 = atomicAdd(Cout, acc) f32 (split-K partial, bias pre-applied elsewhere)
#define KOFF 6291456ull
#define VOFF 13631488ull
template <int EPI>
__global__ __launch_bounds__(256) void gemm_bt(
    const unsigned short* __restrict__ A, const unsigned short* __restrict__ Bw,
    const float* __restrict__ bias, const float* __restrict__ resid,
    void* __restrict__ Cout, int M, int N, int K, int lda, int ldb) {
  __shared__ __align__(16) unsigned short lA[128 * 32];
  __shared__ __align__(16) unsigned short lB[128 * 32];
  const int tid = threadIdx.x;
  const int w = tid >> 6, lane = tid & 63;
  const int lr = lane & 15, lq = lane >> 4;
  const int bm = blockIdx.y, bn = blockIdx.x;
  const unsigned short* Ab = A + (size_t)bm * 128 * lda;
  const unsigned short* Bb = Bw + (size_t)bn * 128 * ldb;
  const int wm = (w & 1) << 6, wn = (w >> 1) << 6;
  f32x4 acc[4][4] = {};
  const int kiters = K >> 5;
  const int c0 = tid, c1 = 256 + tid;
  const int r0 = c0 >> 2, o0 = (c0 & 3) << 3;
  const int r1 = c1 >> 2, o1 = (c1 & 3) << 3;
  for (int kt = 0; kt < kiters; ++kt) {
    const int kb = kt << 5;
    __syncthreads();
    async16(Ab + (size_t)r0 * lda + kb + o0, lA + c0 * 8);
    async16(Bb + (size_t)r0 * ldb + kb + o0, lB + c0 * 8);
    async16(Ab + (size_t)r1 * lda + kb + o1, lA + c1 * 8);
    async16(Bb + (size_t)r1 * ldb + kb + o1, lB + c1 * 8);
    __syncthreads();
    bf16x8 af[4], bfr[4];
#pragma unroll
    for (int i = 0; i < 4; ++i) af[i] = *(const bf16x8*)(lA + (wm + i * 16 + lr) * 32 + lq * 8);
#pragma unroll
    for (int i = 0; i < 4; ++i) bfr[i] = *(const bf16x8*)(lB + (wn + i * 16 + lr) * 32 + lq * 8);
#pragma unroll
    for (int i = 0; i < 4; ++i)
#pragma unroll
      for (int j = 0; j < 4; ++j)
        acc[i][j] = __builtin_amdgcn_mfma_f32_16x16x32_bf16(af[i], bfr[j], acc[i][j], 0, 0, 0);
  }
  const int which = (bn * 128) >> 10;  // EPI5: 0=Q,1=K,2=V (block-uniform; 1024%128==0)
#pragma unroll
  for (int i = 0; i < 4; ++i) {
#pragma unroll
    for (int j = 0; j < 4; ++j) {
      const int colg = bn * 128 + wn + j * 16 + lr;
      const float bi = (EPI == 6) ? 0.f : bias[colg];
      const int rowg0 = bm * 128 + wm + i * 16 + lq * 4;
#pragma unroll
      for (int r = 0; r < 4; ++r) {
        const int rowg = rowg0 + r;
        const float val = acc[i][j][r] + bi;
        if (EPI == 5) {
          const int t = rowg >> 4, bb = rowg & 15;
          const int hh = (colg >> 6) & 15, dd = colg & 63;
          const size_t nn = (size_t)(bb * 16 + hh);
          unsigned short* q16 = (unsigned short*)Cout;
          if (which == 0) {
            if (rowg >= 1024) q16[(nn * 384 + (t - 64)) * 64 + dd] = f2bf(val);
          } else if (which == 1) {
            q16[KOFF + (nn * 448 + t) * 64 + dd] = f2bf(val);
          } else {
            q16[VOFF + (nn * 448 + t) * 64 + dd] = f2bf(val);
          }
        } else {
          const size_t idx = (size_t)rowg * N + colg;
          if (EPI == 2) ((float*)Cout)[idx] = val + resid[idx];
          else if (EPI == 3) ((unsigned short*)Cout)[idx] = f2bf(fmaxf(val, 0.f));
          else if (EPI == 6) atomicAdd(&((float*)Cout)[idx], acc[i][j][r]);
        }
      }
    }
  }
}

// ---------------- V transpose: vb[n][t][d] -> vt[n][d][t] ----------------
__global__ __launch_bounds__(256) void vtrans(const unsigned short* __restrict__ vb,
                                              unsigned short* __restrict__ vt) {
  __shared__ __align__(16) unsigned short ls[64][80];
  const int kc = blockIdx.x, n = blockIdx.y;
  const int tid = threadIdx.x;
#pragma unroll
  for (int i = 0; i < 2; ++i) {
    const int c = i * 256 + tid;
    const int kk = c >> 3, dc = (c & 7) << 3;
    u16x8 val = *(const u16x8*)(vb + ((size_t)n * 448 + kc * 64 + kk) * 64 + dc);
    *(u16x8*)&ls[kk][dc] = val;
  }
  __syncthreads();
#pragma unroll
  for (int i = 0; i < 2; ++i) {
    const int c = i * 256 + tid;
    const int d = c >> 3, kx = (c & 7) << 3;
    u16x8 o;
#pragma unroll
    for (int j = 0; j < 8; ++j) o[j] = ls[kx + j][d];
    *(u16x8*)(vt + ((size_t)n * 64 + d) * 448 + kc * 64 + kx) = o;
  }
}

// ---------------- fused attention: QK^T -> suppression -> softmax -> PV ----------------
// 1D grid 6144 = 8 XCD x 32 heads x 24 qtiles(16 rows). All loads head-major coalesced.
#define SST 456  // S row stride (f32): 456 % 32 == 8 -> phase-1 quad stores 2-way (free)
__global__ __launch_bounds__(256) void attn_kernel(
    const unsigned short* __restrict__ qt_, const unsigned short* __restrict__ kt_,
    const unsigned short* __restrict__ vt_, unsigned short* __restrict__ attn) {
  __shared__ __align__(16) float S[16][SST];  // 29.2 KB -> 5 blocks/CU
  const int id = blockIdx.x;
  const int xcd = id & 7, j0 = id >> 3;
  const int n = xcd * 32 + (j0 & 31), qt = j0 >> 5;
  const int b = n >> 4, h = n & 15;
  const int tid = threadIdx.x, w = tid >> 6, lane = tid & 63;
  const int lr = lane & 15, lq = lane >> 4;

  // Q fragments
  const unsigned short* qp = qt_ + ((size_t)n * 384 + qt * 16 + lr) * 64 + lq * 8;
  const bf16x8 a0 = *(const bf16x8*)qp;
  const bf16x8 a1 = *(const bf16x8*)(qp + 32);

  // phase 1: wave w owns score cols [w*112, w*112+112)
  const int cw = w * 112;
  bf16x8 kb0[7], kb1[7];
#pragma unroll
  for (int nf = 0; nf < 7; ++nf) {
    const unsigned short* kp = kt_ + ((size_t)n * 448 + cw + nf * 16 + lr) * 64 + lq * 8;
    kb0[nf] = *(const bf16x8*)kp;
    kb1[nf] = *(const bf16x8*)(kp + 32);
  }
#pragma unroll
  for (int nf = 0; nf < 7; ++nf) {
    f32x4 acc = {0.f, 0.f, 0.f, 0.f};
    acc = __builtin_amdgcn_mfma_f32_16x16x32_bf16(a0, kb0[nf], acc, 0, 0, 0);
    acc = __builtin_amdgcn_mfma_f32_16x16x32_bf16(a1, kb1[nf], acc, 0, 0, 0);
#pragma unroll
    for (int r = 0; r < 4; ++r) S[lq * 4 + r][cw + nf * 16 + lr] = acc[r];
  }
  __syncthreads();

  // phase 2: softmax + suppression + re-softmax. 2 rows interleaved per chain
  // (independent reduction chains pipeline the ds_swizzle latency).
#pragma unroll
  for (int rg = 0; rg < 2; ++rg) {
    const int r0 = w * 4 + rg * 2, r1 = r0 + 1;
    float e0[7], e1[7];
    float m0 = -3.4e38f, m1 = -3.4e38f;
#pragma unroll
    for (int j = 0; j < 7; ++j) {
      e0[j] = S[r0][lane + 64 * j]; m0 = fmaxf(m0, e0[j]);
      e1[j] = S[r1][lane + 64 * j]; m1 = fmaxf(m1, e1[j]);
    }
#pragma unroll
    for (int off = 32; off; off >>= 1) {
      m0 = fmaxf(m0, __shfl_xor(m0, off));
      m1 = fmaxf(m1, __shfl_xor(m1, off));
    }
    float s0 = 0.f, s1 = 0.f, c0 = 0.f, c1 = 0.f;
#pragma unroll
    for (int j = 0; j < 7; ++j) {
      e0[j] = __expf(e0[j] - m0); s0 += e0[j]; if (e0[j] > 0.f) c0 += 1.f;
      e1[j] = __expf(e1[j] - m1); s1 += e1[j]; if (e1[j] > 0.f) c1 += 1.f;
    }
#pragma unroll
    for (int off = 32; off; off >>= 1) {
      s0 += __shfl_xor(s0, off); s1 += __shfl_xor(s1, off);
      c0 += __shfl_xor(c0, off); c1 += __shfl_xor(c1, off);
    }
    const float inv0 = 1.f / s0, inv1 = 1.f / s1;
    const float mean0 = 1.f / c0, mean1 = 1.f / c1;  // sum(p) == 1 to ~1e-7
    float d0 = 0.f, d1 = 0.f;
#pragma unroll
    for (int j = 0; j < 7; ++j) {
      const float p0 = e0[j] * inv0, p1 = e1[j] * inv1;
      const float dd0 = p0 - mean0, dd1 = p1 - mean1;
      if (p0 > 0.f) d0 += dd0 * dd0;
      if (p1 > 0.f) d1 += dd1 * dd1;
    }
#pragma unroll
    for (int off = 32; off; off >>= 1) {
      d0 += __shfl_xor(d0, off); d1 += __shfl_xor(d1, off);
    }
    const float thr0 = mean0 - 0.5f * sqrtf(d0 / (c0 - 1.f));
    const float thr1 = mean1 - 0.5f * sqrtf(d1 / (c1 - 1.f));
    float t0 = 0.f, t1 = 0.f;
#pragma unroll
    for (int j = 0; j < 7; ++j) {
      if (!(e0[j] * inv0 < thr0)) t0 += e0[j];
      if (!(e1[j] * inv1 < thr1)) t1 += e1[j];
    }
#pragma unroll
    for (int off = 32; off; off >>= 1) {
      t0 += __shfl_xor(t0, off); t1 += __shfl_xor(t1, off);
    }
    const float i20 = 1.f / t0, i21 = 1.f / t1;
    unsigned short* p0w = (unsigned short*)&S[r0][0];
    unsigned short* p1w = (unsigned short*)&S[r1][0];
#pragma unroll
    for (int j = 0; j < 7; ++j) {
      p0w[lane + 64 * j] = (e0[j] * inv0 < thr0) ? (unsigned short)0 : f2bf(e0[j] * i20);
      p1w[lane + 64 * j] = (e1[j] * inv1 < thr1) ? (unsigned short)0 : f2bf(e1[j] * i21);
    }
  }
  __syncthreads();

  // phase 3: PV. wave w owns d-slice [w*16, w*16+16). P is bf16 rows of S (stride 2*SST u16).
  const unsigned short* Pb = (const unsigned short*)&S[0][0];
  bf16x8 vb0[7], vb1[7];
#pragma unroll
  for (int kt2 = 0; kt2 < 7; ++kt2) {
    const unsigned short* vp = vt_ + ((size_t)n * 64 + w * 16 + lr) * 448 + kt2 * 64 + lq * 8;
    vb0[kt2] = *(const bf16x8*)vp;
    vb1[kt2] = *(const bf16x8*)(vp + 32);
  }
  f32x4 acc3 = {0.f, 0.f, 0.f, 0.f};
#pragma unroll
  for (int kt2 = 0; kt2 < 7; ++kt2) {
    const bf16x8 af0 = *(const bf16x8*)(Pb + (size_t)lr * (2 * SST) + kt2 * 64 + lq * 8);
    const bf16x8 af1 = *(const bf16x8*)(Pb + (size_t)lr * (2 * SST) + kt2 * 64 + 32 + lq * 8);
    acc3 = __builtin_amdgcn_mfma_f32_16x16x32_bf16(af0, vb0[kt2], acc3, 0, 0, 0);
    acc3 = __builtin_amdgcn_mfma_f32_16x16x32_bf16(af1, vb1[kt2], acc3, 0, 0, 0);
  }
#pragma unroll
  for (int r = 0; r < 4; ++r) {
    const int l = qt * 16 + lq * 4 + r;
    attn[((size_t)l * 16 + b) * 1024 + h * 64 + w * 16 + lr] = f2bf(acc3[r]);
  }
}

// ---------------- launch ----------------
extern "C" void kernel_launch(void* const* d_in, const int* in_sizes, int n_in,
                              void* d_out, int out_size, void* d_ws, size_t ws_size,
                              hipStream_t stream) {
  (void)in_sizes; (void)n_in; (void)out_size; (void)ws_size;
  const float* x    = (const float*)d_in[0];
  const float* mem  = (const float*)d_in[1];
  const float* q_w  = (const float*)d_in[2];
  const float* q_b  = (const float*)d_in[3];
  const float* k_w  = (const float*)d_in[4];
  const float* k_b  = (const float*)d_in[5];
  const float* v_w  = (const float*)d_in[6];
  const float* v_b  = (const float*)d_in[7];
  const float* o_w  = (const float*)d_in[8];
  const float* o_b  = (const float*)d_in[9];
  const float* ln1w = (const float*)d_in[10];
  const float* ln1b = (const float*)d_in[11];
  const float* f1w  = (const float*)d_in[12];
  const float* f1b  = (const float*)d_in[13];
  const float* f2w  = (const float*)d_in[14];
  const float* f2b  = (const float*)d_in[15];
  const float* ln2w = (const float*)d_in[16];
  const float* ln2b = (const float*)d_in[17];

  unsigned short* WQ   = (unsigned short*)d_ws;        // 3x 1048576 contiguous = fused B
  unsigned short* WK   = WQ + 1048576;
  unsigned short* WV   = WK + 1048576;
  unsigned short* WO   = WV + 1048576;
  unsigned short* WF1  = WO + 1048576;                 // 4194304
  unsigned short* WF2  = WF1 + 4194304;                // 4194304
  unsigned short* ABUF = WF2 + 4194304;                // 7340032 (mem rows 0..1023, xn rows 1024..7167)
  unsigned short* QB   = ABUF + 7340032;               // 6291456 [n][384][64]; KB/VB at KOFF/VOFF
  unsigned short* KB   = QB + 6291456;                 // 7340032 [n][448][64]
  unsigned short* VB   = KB + 7340032;                 // 7340032 [n][448][64]
  unsigned short* VT   = VB + 7340032;                 // 7340032 [n][64][448]
  unsigned short* ATTN = VT + 7340032;                 // 6291456
  float*          X2   = (float*)(ATTN + 6291456);     // 6291456 f32
  float*          QKVB = (float*)ATTN;                 // 3072 f32, dead before attn writes ATTN
  unsigned short* XN2  = ATTN;                         // alias (attn dead after out-proj)
  unsigned short* HB   = ABUF;                         // alias (A/q/k/v staging dead after attention)

  // weight + memory converts (0.125 q-scale folded into weights+bias)
  cvt_bf16<<<1024, 256, 0, stream>>>(q_w, WQ, 262144, 0.125f);
  cvt_bf16<<<1024, 256, 0, stream>>>(k_w, WK, 262144, 1.f);
  cvt_bf16<<<1024, 256, 0, stream>>>(v_w, WV, 262144, 1.f);
  cvt_bf16<<<1024, 256, 0, stream>>>(o_w, WO, 262144, 1.f);
  cvt_bf16<<<4096, 256, 0, stream>>>(f1w, WF1, 1048576, 1.f);
  cvt_bf16<<<4096, 256, 0, stream>>>(f2w, WF2, 1048576, 1.f);
  cvt_bf16<<<1024, 256, 0, stream>>>(mem, ABUF, 262144, 1.f);
  concat_bias<<<12, 256, 0, stream>>>(q_b, k_b, v_b, QKVB);

  // LN1 -> xn (rows 1024.. of ABUF)
  ln_bf16<0><<<6144, 256, 0, stream>>>(x, ABUF + 1048576, ln1w, ln1b, nullptr, nullptr);

  // fused QKV: [mem;xn] x [Wq;Wk;Wv]^T, head-major epilogue (summary row is dead code)
  gemm_bt<5><<<dim3(24, 56), 256, 0, stream>>>(ABUF, WQ, QKVB, nullptr, QB, 7168, 3072, 1024, 1024, 1024);

  vtrans<<<dim3(7, 256), 256, 0, stream>>>(VB, VT);
  attn_kernel<<<6144, 256, 0, stream>>>(QB, KB, VT, ATTN);

  // out-proj + residual -> X2 (f32)
  gemm_bt<2><<<dim3(8, 48), 256, 0, stream>>>(ATTN, WO, o_b, x, X2, 6144, 1024, 1024, 1024, 1024);

  // LN2 -> xn2, and prefill d_out = X2 + fc2_bias (for split-K atomic fc2)
  ln_bf16<1><<<6144, 256, 0, stream>>>(X2, XN2, ln2w, ln2b, f2b, (float*)d_out);

  // FFN
  gemm_bt<3><<<dim3(32, 48), 256, 0, stream>>>(XN2, WF1, f1b, nullptr, HB, 6144, 4096, 1024, 1024, 1024);
  // fc2 split-K=2, atomicAdd partials into prefilled d_out
  gemm_bt<6><<<dim3(8, 48), 256, 0, stream>>>(HB,        WF2,        nullptr, nullptr, d_out, 6144, 1024, 2048, 4096, 4096);
  gemm_bt<6><<<dim3(8, 48), 256, 0, stream>>>(HB + 2048, WF2 + 2048, nullptr, nullptr, d_out, 6144, 1024, 2048, 4096, 4096);
}